// Round 3
// baseline (2156.185 us; speedup 1.0000x reference)
//
#include <hip/hip_runtime.h>
#include <hip/hip_bf16.h>

typedef __bf16 bf16_t;
typedef __attribute__((ext_vector_type(8))) __bf16 bf16x8;
typedef __attribute__((ext_vector_type(4))) float f32x4;

#define DIM 128
#define LDSPITCH 132   // 128 + 4 pad: keeps 16B alignment, breaks bank conflicts

// ---------------- weight prep: Wc[s][n][k256] bf16, s = layer*2 + type ----------
__global__ void prep_weights(const float* __restrict__ Wl, const float* __restrict__ Wr,
                             bf16_t* __restrict__ Wc) {
    int idx = blockIdx.x * blockDim.x + threadIdx.x;   // over 6*128*256
    if (idx >= 6 * 128 * 256) return;
    int k = idx & 255;
    int n = (idx >> 8) & 127;
    int s = idx >> 15;                                  // 0..5
    float v;
    if (k < 128) v = Wl[((size_t)s * 128 + n) * 128 + k];
    else         v = Wr[((size_t)s * 128 + n) * 128 + (k - 128)];
    Wc[idx] = (bf16_t)v;
}

// ---------------- degree count + inverse ----------------
__global__ void count_edges(const int* __restrict__ dst, int* __restrict__ cnt, int E) {
    int i = blockIdx.x * blockDim.x + threadIdx.x;
    if (i < E) atomicAdd(&cnt[dst[i]], 1);
}

__global__ void make_inv(const int* __restrict__ cnt, float* __restrict__ inv, int n) {
    int i = blockIdx.x * blockDim.x + threadIdx.x;
    if (i < n) inv[i] = 1.0f / (float)max(cnt[i], 1);
}

// ---------------- CSR build: block scan ----------------
__global__ __launch_bounds__(256) void scan_local(const int* __restrict__ cnt,
                                                  int* __restrict__ partial,
                                                  int* __restrict__ blocksum, int M) {
    __shared__ int sdata[256];
    int i = blockIdx.x * 256 + threadIdx.x;
    int v = (i < M) ? cnt[i] : 0;
    sdata[threadIdx.x] = v;
    __syncthreads();
    for (int off = 1; off < 256; off <<= 1) {
        int t = (threadIdx.x >= off) ? sdata[threadIdx.x - off] : 0;
        __syncthreads();
        sdata[threadIdx.x] += t;
        __syncthreads();
    }
    int incl = sdata[threadIdx.x];
    if (i < M) partial[i] = incl - v;
    if (threadIdx.x == 255) blocksum[blockIdx.x] = incl;
}

__global__ __launch_bounds__(256) void scan_blocks(int* __restrict__ blocksum, int NB) {
    __shared__ int sdata[256];
    __shared__ int running;
    if (threadIdx.x == 0) running = 0;
    __syncthreads();
    for (int base = 0; base < NB; base += 256) {
        int i = base + threadIdx.x;
        int v = (i < NB) ? blocksum[i] : 0;
        sdata[threadIdx.x] = v;
        __syncthreads();
        for (int off = 1; off < 256; off <<= 1) {
            int t = (threadIdx.x >= off) ? sdata[threadIdx.x - off] : 0;
            __syncthreads();
            sdata[threadIdx.x] += t;
            __syncthreads();
        }
        int incl = sdata[threadIdx.x];
        int r = running;
        __syncthreads();
        if (i < NB) blocksum[i] = incl - v + r;
        if (threadIdx.x == 0) running = r + sdata[255];
        __syncthreads();
    }
}

__global__ void add_offsets(const int* __restrict__ partial, const int* __restrict__ blocksum,
                            int* __restrict__ rowstart, int* __restrict__ cursor, int M) {
    int i = blockIdx.x * blockDim.x + threadIdx.x;
    if (i < M) {
        int rs = partial[i] + blocksum[i >> 8];
        rowstart[i] = rs;
        cursor[i] = rs;
    }
}

__global__ void bin_edges(const int* __restrict__ src, const int* __restrict__ dst,
                          int* __restrict__ cursor, int* __restrict__ csr_src,
                          int* __restrict__ csr_dst, int E) {
    int e = blockIdx.x * blockDim.x + threadIdx.x;
    if (e < E) {
        int d = dst[e];
        int pos = atomicAdd(&cursor[d], 1);
        csr_src[pos] = src[e];
        csr_dst[pos] = d;
    }
}

// ---------------- fused SAGE: gather(mean) into LDS + MFMA GEMM ----------------
// out[d] = mean_{s in N(d)} xsrc[s] @ Wl.T + bias + xdst[d] @ Wr.T  (+ReLU)
// Block = 64 dst rows, 4 waves. Wave w owns output cols [w*32, w*32+32).
template <bool RELU>
__global__ __launch_bounds__(256) void sage_fused(
    const float* __restrict__ xsrc, const float* __restrict__ xdst,
    const int* __restrict__ rowstart, const int* __restrict__ csr_src,
    const int* __restrict__ csr_dst, const float* __restrict__ inv,
    const bf16_t* __restrict__ Wc, const float* __restrict__ bias,
    float* __restrict__ out, int M, int E) {
    __shared__ float lds_a[64 * LDSPITCH];

    const int tid  = threadIdx.x;
    const int wave = tid >> 6;
    const int lane = tid & 63;
    const int quad = lane >> 4;
    const int l16  = lane & 15;
    const int d0   = blockIdx.x * 64;

    // --- load this wave's B-slice first: overlaps with gather latency ---
    // B layout for mfma_16x16x32: B[k = quad*8+j][n = l16]; Wc is [n][k] row-major
    bf16x8 breg[2][8];
#pragma unroll
    for (int ct = 0; ct < 2; ++ct)
#pragma unroll
        for (int kt = 0; kt < 8; ++kt)
            breg[ct][kt] = *(const bf16x8*)(
                Wc + ((size_t)(wave * 32 + ct * 16 + l16)) * 256 + kt * 32 + quad * 8);

    // --- zero LDS tile ---
    for (int i = tid; i < 64 * LDSPITCH; i += 256) lds_a[i] = 0.f;
    __syncthreads();

    // --- gather phase: edge-parallel, contiguous CSR range for this dst block ---
    int e0 = rowstart[d0];
    int e1 = (d0 + 64 < M) ? rowstart[d0 + 64] : E;
    int ne = e1 - e0;
    int chunk = (ne + 3) >> 2;
    int es = e0 + wave * chunk;
    int ee = min(es + chunk, e1);
#pragma unroll 4
    for (int e = es; e < ee; ++e) {
        int s  = csr_src[e];
        int dl = csr_dst[e] - d0;
        float2 v = ((const float2*)(xsrc + (size_t)s * DIM))[lane];
        float* ap = lds_a + dl * LDSPITCH + lane * 2;
        atomicAdd(ap,     v.x);
        atomicAdd(ap + 1, v.y);
    }
    __syncthreads();

    // --- GEMM phase: each wave 64 rows x 32 cols ---
    f32x4 acc[4][2];
#pragma unroll
    for (int rt = 0; rt < 4; ++rt) {
        acc[rt][0] = (f32x4){0.f, 0.f, 0.f, 0.f};
        acc[rt][1] = (f32x4){0.f, 0.f, 0.f, 0.f};
    }

#pragma unroll
    for (int rt = 0; rt < 4; ++rt) {
        int rloc = rt * 16 + l16;
        int grow = d0 + rloc; if (grow >= M) grow = M - 1;
        float invn = inv[grow];
        const float*  lrow = lds_a + rloc * LDSPITCH;
        const float*  drow = xdst + (size_t)grow * DIM;
#pragma unroll
        for (int kt = 0; kt < 8; ++kt) {
            float4 a0, a1;
            if (kt < 4) {
                const float4* p = (const float4*)(lrow + kt * 32 + quad * 8);
                a0 = p[0]; a1 = p[1];
                a0.x *= invn; a0.y *= invn; a0.z *= invn; a0.w *= invn;
                a1.x *= invn; a1.y *= invn; a1.z *= invn; a1.w *= invn;
            } else {
                const float4* p = (const float4*)(drow + (kt - 4) * 32 + quad * 8);
                a0 = p[0]; a1 = p[1];
            }
            bf16x8 af;
            af[0] = (bf16_t)a0.x; af[1] = (bf16_t)a0.y;
            af[2] = (bf16_t)a0.z; af[3] = (bf16_t)a0.w;
            af[4] = (bf16_t)a1.x; af[5] = (bf16_t)a1.y;
            af[6] = (bf16_t)a1.z; af[7] = (bf16_t)a1.w;
            acc[rt][0] = __builtin_amdgcn_mfma_f32_16x16x32_bf16(af, breg[0][kt], acc[rt][0], 0, 0, 0);
            acc[rt][1] = __builtin_amdgcn_mfma_f32_16x16x32_bf16(af, breg[1][kt], acc[rt][1], 0, 0, 0);
        }
    }

    // --- epilogue: C/D layout col = lane&15, row = quad*4 + reg ---
#pragma unroll
    for (int ct = 0; ct < 2; ++ct) {
        int col = wave * 32 + ct * 16 + l16;
        float b = bias[col];
#pragma unroll
        for (int rt = 0; rt < 4; ++rt)
#pragma unroll
            for (int r = 0; r < 4; ++r) {
                int row = d0 + rt * 16 + quad * 4 + r;
                if (row < M) {
                    float v = acc[rt][ct][r] + b;
                    if (RELU) v = fmaxf(v, 0.f);
                    out[(size_t)row * DIM + col] = v;
                }
            }
    }
}

// ---------------- launch ----------------
extern "C" void kernel_launch(void* const* d_in, const int* in_sizes, int n_in,
                              void* d_out, int out_size, void* d_ws, size_t ws_size,
                              hipStream_t stream) {
    const float* x_m = (const float*)d_in[0];
    const float* x_t = (const float*)d_in[1];
    const float* Wl  = (const float*)d_in[2];
    const float* bl  = (const float*)d_in[3];
    const float* Wr  = (const float*)d_in[4];
    const int* e_mt  = (const int*)d_in[5];
    const int* e_tm  = (const int*)d_in[6];

    const int Mm = in_sizes[0] / DIM;     // 100000
    const int Mt = in_sizes[1] / DIM;     // 100000
    const int E  = in_sizes[5] / 2;       // 400000
    const int NBt = (Mt + 255) / 256;
    const int NBm = (Mm + 255) / 256;

    float* out_m = (float*)d_out;
    float* out_t = (float*)d_out + (size_t)Mm * DIM;

    char* ws = (char*)d_ws;
    size_t off = 0;
    auto alloc = [&](size_t bytes) -> void* {
        void* p = ws + off;
        off += (bytes + 255) & ~(size_t)255;
        return p;
    };
    float*  xm2    = (float*)alloc((size_t)Mm * DIM * 4);
    float*  xt2    = (float*)alloc((size_t)Mt * DIM * 4);
    float*  inv_t  = (float*)alloc((size_t)Mt * 4);
    float*  inv_m  = (float*)alloc((size_t)Mm * 4);
    int*    cnt_t  = (int*)alloc((size_t)Mt * 4);
    int*    cnt_m  = (int*)alloc((size_t)Mm * 4);
    int*    rs_t   = (int*)alloc((size_t)Mt * 4);
    int*    rs_m   = (int*)alloc((size_t)Mm * 4);
    int*    cur_tb = (int*)alloc((size_t)Mt * 4);
    int*    cur_mb = (int*)alloc((size_t)Mm * 4);
    int*    partial= (int*)alloc((size_t)((Mm > Mt) ? Mm : Mt) * 4);
    int*    bsum   = (int*)alloc((size_t)((NBt > NBm) ? NBt : NBm) * 4);
    int*    csr_t  = (int*)alloc((size_t)E * 4);
    int*    csrd_t = (int*)alloc((size_t)E * 4);
    int*    csr_m  = (int*)alloc((size_t)E * 4);
    int*    csrd_m = (int*)alloc((size_t)E * 4);
    bf16_t* Wc     = (bf16_t*)alloc((size_t)6 * 128 * 256 * 2);

    // ---- per-launch structure prep ----
    hipMemsetAsync(cnt_t, 0, (size_t)Mt * 4, stream);
    hipMemsetAsync(cnt_m, 0, (size_t)Mm * 4, stream);
    prep_weights<<<(6 * 128 * 256 + 255) / 256, 256, 0, stream>>>(Wl, Wr, Wc);
    count_edges<<<(E + 255) / 256, 256, 0, stream>>>(e_mt + E, cnt_t, E);
    count_edges<<<(E + 255) / 256, 256, 0, stream>>>(e_tm + E, cnt_m, E);
    make_inv<<<(Mt + 255) / 256, 256, 0, stream>>>(cnt_t, inv_t, Mt);
    make_inv<<<(Mm + 255) / 256, 256, 0, stream>>>(cnt_m, inv_m, Mm);

    // CSR for edge_mt (dst = track)
    scan_local<<<NBt, 256, 0, stream>>>(cnt_t, partial, bsum, Mt);
    scan_blocks<<<1, 256, 0, stream>>>(bsum, NBt);
    add_offsets<<<NBt, 256, 0, stream>>>(partial, bsum, rs_t, cur_tb, Mt);
    bin_edges<<<(E + 255) / 256, 256, 0, stream>>>(e_mt, e_mt + E, cur_tb, csr_t, csrd_t, E);

    // CSR for edge_tm (dst = musician)
    scan_local<<<NBm, 256, 0, stream>>>(cnt_m, partial, bsum, Mm);
    scan_blocks<<<1, 256, 0, stream>>>(bsum, NBm);
    add_offsets<<<NBm, 256, 0, stream>>>(partial, bsum, rs_m, cur_mb, Mm);
    bin_edges<<<(E + 255) / 256, 256, 0, stream>>>(e_tm, e_tm + E, cur_mb, csr_m, csrd_m, E);

    const float* cm = x_m;
    const float* ct = x_t;
    for (int layer = 0; layer < 3; ++layer) {
        float *nxt_m, *nxt_t;
        if (layer == 1) { nxt_m = xm2;   nxt_t = xt2;   }
        else            { nxt_m = out_m; nxt_t = out_t; }
        const float* biasT = bl + ((size_t)layer * 2 + 0) * DIM;
        const float* biasM = bl + ((size_t)layer * 2 + 1) * DIM;
        const bf16_t* WcT = Wc + ((size_t)layer * 2 + 0) * 128 * 256;
        const bf16_t* WcM = Wc + ((size_t)layer * 2 + 1) * 128 * 256;

        // edge type 0: musician -> track (dst = track)
        if (layer < 2)
            sage_fused<true ><<<(Mt + 63) / 64, 256, 0, stream>>>(
                cm, ct, rs_t, csr_t, csrd_t, inv_t, WcT, biasT, nxt_t, Mt, E);
        else
            sage_fused<false><<<(Mt + 63) / 64, 256, 0, stream>>>(
                cm, ct, rs_t, csr_t, csrd_t, inv_t, WcT, biasT, nxt_t, Mt, E);

        // edge type 1: track -> musician (dst = musician)
        if (layer < 2)
            sage_fused<true ><<<(Mm + 63) / 64, 256, 0, stream>>>(
                ct, cm, rs_m, csr_m, csrd_m, inv_m, WcM, biasM, nxt_m, Mm, E);
        else
            sage_fused<false><<<(Mm + 63) / 64, 256, 0, stream>>>(
                ct, cm, rs_m, csr_m, csrd_m, inv_m, WcM, biasM, nxt_m, Mm, E);

        cm = nxt_m;
        ct = nxt_t;
    }
}

// Round 4
// 826.048 us; speedup vs baseline: 2.6102x; 2.6102x over previous
//
#include <hip/hip_runtime.h>
#include <hip/hip_bf16.h>

typedef __bf16 bf16_t;
typedef __attribute__((ext_vector_type(4))) __bf16 bf16x4;
typedef __attribute__((ext_vector_type(8))) __bf16 bf16x8;
typedef __attribute__((ext_vector_type(4))) float f32x4;

#define DIM 128

// ---------------- weight prep: Wc[s][n][k256] bf16, s = layer*2 + type ----------
__global__ void prep_weights(const float* __restrict__ Wl, const float* __restrict__ Wr,
                             bf16_t* __restrict__ Wc) {
    int idx = blockIdx.x * blockDim.x + threadIdx.x;   // over 6*128*256
    if (idx >= 6 * 128 * 256) return;
    int k = idx & 255;
    int n = (idx >> 8) & 127;
    int s = idx >> 15;                                  // 0..5
    float v;
    if (k < 128) v = Wl[((size_t)s * 128 + n) * 128 + k];
    else         v = Wr[((size_t)s * 128 + n) * 128 + (k - 128)];
    Wc[idx] = (bf16_t)v;
}

// ---------------- degree count ----------------
__global__ void count_edges(const int* __restrict__ dst, int* __restrict__ cnt, int E) {
    int i = blockIdx.x * blockDim.x + threadIdx.x;
    if (i < E) atomicAdd(&cnt[dst[i]], 1);
}

// ---------------- CSR build: block scan ----------------
__global__ __launch_bounds__(256) void scan_local(const int* __restrict__ cnt,
                                                  int* __restrict__ partial,
                                                  int* __restrict__ blocksum, int M) {
    __shared__ int sdata[256];
    int i = blockIdx.x * 256 + threadIdx.x;
    int v = (i < M) ? cnt[i] : 0;
    sdata[threadIdx.x] = v;
    __syncthreads();
    for (int off = 1; off < 256; off <<= 1) {
        int t = (threadIdx.x >= off) ? sdata[threadIdx.x - off] : 0;
        __syncthreads();
        sdata[threadIdx.x] += t;
        __syncthreads();
    }
    int incl = sdata[threadIdx.x];
    if (i < M) partial[i] = incl - v;
    if (threadIdx.x == 255) blocksum[blockIdx.x] = incl;
}

__global__ __launch_bounds__(256) void scan_blocks(int* __restrict__ blocksum, int NB) {
    __shared__ int sdata[256];
    __shared__ int running;
    if (threadIdx.x == 0) running = 0;
    __syncthreads();
    for (int base = 0; base < NB; base += 256) {
        int i = base + threadIdx.x;
        int v = (i < NB) ? blocksum[i] : 0;
        sdata[threadIdx.x] = v;
        __syncthreads();
        for (int off = 1; off < 256; off <<= 1) {
            int t = (threadIdx.x >= off) ? sdata[threadIdx.x - off] : 0;
            __syncthreads();
            sdata[threadIdx.x] += t;
            __syncthreads();
        }
        int incl = sdata[threadIdx.x];
        int r = running;
        __syncthreads();
        if (i < NB) blocksum[i] = incl - v + r;
        if (threadIdx.x == 0) running = r + sdata[255];
        __syncthreads();
    }
}

__global__ void add_offsets(const int* __restrict__ partial, const int* __restrict__ blocksum,
                            int* __restrict__ rowstart, int* __restrict__ cursor, int M) {
    int i = blockIdx.x * blockDim.x + threadIdx.x;
    if (i < M) {
        int rs = partial[i] + blocksum[i >> 8];
        rowstart[i] = rs;
        cursor[i] = rs;
    }
}

__global__ void bin_edges(const int* __restrict__ src, const int* __restrict__ dst,
                          int* __restrict__ cursor, int* __restrict__ csr_src, int E) {
    int e = blockIdx.x * blockDim.x + threadIdx.x;
    if (e < E) {
        int d = dst[e];
        int pos = atomicAdd(&cursor[d], 1);
        csr_src[pos] = src[e];
    }
}

// ---------------- gather-mean -> bf16: 2 dst rows per wave, float4 per lane ------
__global__ __launch_bounds__(256) void gather_mean_bf16(
    const float* __restrict__ xsrc, const int* __restrict__ rowstart,
    const int* __restrict__ cnt, const int* __restrict__ csr_src,
    bf16_t* __restrict__ agg, int M) {
    int wid  = (blockIdx.x * 256 + threadIdx.x) >> 6;
    int lane = threadIdx.x & 63;
    int half = lane >> 5;
    int l32  = lane & 31;
    int d = wid * 2 + half;
    if (d >= M) return;
    int start = rowstart[d];
    int n = cnt[d];
    float4 acc0 = {0.f, 0.f, 0.f, 0.f};
    float4 acc1 = {0.f, 0.f, 0.f, 0.f};
    int k = 0;
    for (; k + 1 < n; k += 2) {
        int s0 = csr_src[start + k];
        int s1 = csr_src[start + k + 1];
        float4 v0 = ((const float4*)(xsrc + (size_t)s0 * DIM))[l32];
        float4 v1 = ((const float4*)(xsrc + (size_t)s1 * DIM))[l32];
        acc0.x += v0.x; acc0.y += v0.y; acc0.z += v0.z; acc0.w += v0.w;
        acc1.x += v1.x; acc1.y += v1.y; acc1.z += v1.z; acc1.w += v1.w;
    }
    if (k < n) {
        int s = csr_src[start + k];
        float4 v = ((const float4*)(xsrc + (size_t)s * DIM))[l32];
        acc0.x += v.x; acc0.y += v.y; acc0.z += v.z; acc0.w += v.w;
    }
    float invn = 1.0f / (float)max(n, 1);
    bf16x4 r;
    r[0] = (bf16_t)((acc0.x + acc1.x) * invn);
    r[1] = (bf16_t)((acc0.y + acc1.y) * invn);
    r[2] = (bf16_t)((acc0.z + acc1.z) * invn);
    r[3] = (bf16_t)((acc0.w + acc1.w) * invn);
    *(bf16x4*)(agg + (size_t)d * DIM + l32 * 4) = r;
}

// ---------------- fused GEMM: out = A0bf@Wl.T + bias + A1@Wr.T (+ReLU) ----------
// A0bf [M,128] bf16 (pre-scaled mean), A1 [M,128] f32.
// Wc [128 n][256 k] bf16 (k<128 Wl, k>=128 Wr).
// Block = 64 rows x 4 waves; wave w owns cols [w*32, w*32+32), B held in VGPRs.
template <bool RELU>
__global__ __launch_bounds__(256) void gemm_fused(
    const bf16_t* __restrict__ A0bf, const float* __restrict__ A1,
    const bf16_t* __restrict__ Wc, const float* __restrict__ bias,
    float* __restrict__ out, int M) {
    const int wave = threadIdx.x >> 6;
    const int lane = threadIdx.x & 63;
    const int quad = lane >> 4;
    const int l16  = lane & 15;
    const int d0   = blockIdx.x * 64;

    // B-slice resident in registers: B[k=quad*8+j][n=l16] from row-major Wc[n][k]
    bf16x8 breg[2][8];
#pragma unroll
    for (int ct = 0; ct < 2; ++ct)
#pragma unroll
        for (int kt = 0; kt < 8; ++kt)
            breg[ct][kt] = *(const bf16x8*)(
                Wc + ((size_t)(wave * 32 + ct * 16 + l16)) * 256 + kt * 32 + quad * 8);

    f32x4 acc[4][2];
#pragma unroll
    for (int rt = 0; rt < 4; ++rt) {
        acc[rt][0] = (f32x4){0.f, 0.f, 0.f, 0.f};
        acc[rt][1] = (f32x4){0.f, 0.f, 0.f, 0.f};
    }

#pragma unroll
    for (int rt = 0; rt < 4; ++rt) {
        int row = d0 + rt * 16 + l16;
        if (row >= M) row = M - 1;          // clamp; stores guarded
        // A-frag loads: independent, issued together
        bf16x8 alo[4];
        const bf16_t* arow = A0bf + (size_t)row * DIM + quad * 8;
#pragma unroll
        for (int kt = 0; kt < 4; ++kt)
            alo[kt] = *(const bf16x8*)(arow + kt * 32);
        float4 fhi[8];
        const float* drow = A1 + (size_t)row * DIM + quad * 8;
#pragma unroll
        for (int kt = 0; kt < 4; ++kt) {
            fhi[kt * 2]     = ((const float4*)(drow + kt * 32))[0];
            fhi[kt * 2 + 1] = ((const float4*)(drow + kt * 32))[1];
        }
        bf16x8 ahi[4];
#pragma unroll
        for (int kt = 0; kt < 4; ++kt) {
            float4 a0 = fhi[kt * 2], a1 = fhi[kt * 2 + 1];
            bf16x8 af;
            af[0] = (bf16_t)a0.x; af[1] = (bf16_t)a0.y;
            af[2] = (bf16_t)a0.z; af[3] = (bf16_t)a0.w;
            af[4] = (bf16_t)a1.x; af[5] = (bf16_t)a1.y;
            af[6] = (bf16_t)a1.z; af[7] = (bf16_t)a1.w;
            ahi[kt] = af;
        }
#pragma unroll
        for (int kt = 0; kt < 4; ++kt) {
            acc[rt][0] = __builtin_amdgcn_mfma_f32_16x16x32_bf16(alo[kt], breg[0][kt], acc[rt][0], 0, 0, 0);
            acc[rt][1] = __builtin_amdgcn_mfma_f32_16x16x32_bf16(alo[kt], breg[1][kt], acc[rt][1], 0, 0, 0);
        }
#pragma unroll
        for (int kt = 0; kt < 4; ++kt) {
            acc[rt][0] = __builtin_amdgcn_mfma_f32_16x16x32_bf16(ahi[kt], breg[0][kt + 4], acc[rt][0], 0, 0, 0);
            acc[rt][1] = __builtin_amdgcn_mfma_f32_16x16x32_bf16(ahi[kt], breg[1][kt + 4], acc[rt][1], 0, 0, 0);
        }
    }

    // epilogue: C/D layout col = lane&15, row = quad*4 + reg
#pragma unroll
    for (int ct = 0; ct < 2; ++ct) {
        int col = wave * 32 + ct * 16 + l16;
        float b = bias[col];
#pragma unroll
        for (int rt = 0; rt < 4; ++rt)
#pragma unroll
            for (int r = 0; r < 4; ++r) {
                int row = d0 + rt * 16 + quad * 4 + r;
                if (row < M) {
                    float v = acc[rt][ct][r] + b;
                    if (RELU) v = fmaxf(v, 0.f);
                    out[(size_t)row * DIM + col] = v;
                }
            }
    }
}

// ---------------- launch ----------------
extern "C" void kernel_launch(void* const* d_in, const int* in_sizes, int n_in,
                              void* d_out, int out_size, void* d_ws, size_t ws_size,
                              hipStream_t stream) {
    const float* x_m = (const float*)d_in[0];
    const float* x_t = (const float*)d_in[1];
    const float* Wl  = (const float*)d_in[2];
    const float* bl  = (const float*)d_in[3];
    const float* Wr  = (const float*)d_in[4];
    const int* e_mt  = (const int*)d_in[5];
    const int* e_tm  = (const int*)d_in[6];

    const int Mm = in_sizes[0] / DIM;     // 100000
    const int Mt = in_sizes[1] / DIM;     // 100000
    const int E  = in_sizes[5] / 2;       // 400000
    const int NBt = (Mt + 255) / 256;
    const int NBm = (Mm + 255) / 256;

    float* out_m = (float*)d_out;
    float* out_t = (float*)d_out + (size_t)Mm * DIM;

    char* ws = (char*)d_ws;
    size_t off = 0;
    auto alloc = [&](size_t bytes) -> void* {
        void* p = ws + off;
        off += (bytes + 255) & ~(size_t)255;
        return p;
    };
    float*  xm2    = (float*)alloc((size_t)Mm * DIM * 4);
    float*  xt2    = (float*)alloc((size_t)Mt * DIM * 4);
    bf16_t* agg    = (bf16_t*)alloc((size_t)((Mm > Mt) ? Mm : Mt) * DIM * 2);
    int*    cnt_t  = (int*)alloc((size_t)Mt * 4);
    int*    cnt_m  = (int*)alloc((size_t)Mm * 4);
    int*    rs_t   = (int*)alloc((size_t)Mt * 4);
    int*    rs_m   = (int*)alloc((size_t)Mm * 4);
    int*    cur_tb = (int*)alloc((size_t)Mt * 4);
    int*    cur_mb = (int*)alloc((size_t)Mm * 4);
    int*    partial= (int*)alloc((size_t)((Mm > Mt) ? Mm : Mt) * 4);
    int*    bsum   = (int*)alloc((size_t)((NBt > NBm) ? NBt : NBm) * 4);
    int*    csr_t  = (int*)alloc((size_t)E * 4);
    int*    csr_m  = (int*)alloc((size_t)E * 4);
    bf16_t* Wc     = (bf16_t*)alloc((size_t)6 * 128 * 256 * 2);

    // ---- per-launch structure prep ----
    hipMemsetAsync(cnt_t, 0, (size_t)Mt * 4, stream);
    hipMemsetAsync(cnt_m, 0, (size_t)Mm * 4, stream);
    prep_weights<<<(6 * 128 * 256 + 255) / 256, 256, 0, stream>>>(Wl, Wr, Wc);
    count_edges<<<(E + 255) / 256, 256, 0, stream>>>(e_mt + E, cnt_t, E);
    count_edges<<<(E + 255) / 256, 256, 0, stream>>>(e_tm + E, cnt_m, E);

    // CSR for edge_mt (dst = track)
    scan_local<<<NBt, 256, 0, stream>>>(cnt_t, partial, bsum, Mt);
    scan_blocks<<<1, 256, 0, stream>>>(bsum, NBt);
    add_offsets<<<NBt, 256, 0, stream>>>(partial, bsum, rs_t, cur_tb, Mt);
    bin_edges<<<(E + 255) / 256, 256, 0, stream>>>(e_mt, e_mt + E, cur_tb, csr_t, E);

    // CSR for edge_tm (dst = musician)
    scan_local<<<NBm, 256, 0, stream>>>(cnt_m, partial, bsum, Mm);
    scan_blocks<<<1, 256, 0, stream>>>(bsum, NBm);
    add_offsets<<<NBm, 256, 0, stream>>>(partial, bsum, rs_m, cur_mb, Mm);
    bin_edges<<<(E + 255) / 256, 256, 0, stream>>>(e_tm, e_tm + E, cur_mb, csr_m, E);

    const float* cm = x_m;
    const float* ct = x_t;
    for (int layer = 0; layer < 3; ++layer) {
        float *nxt_m, *nxt_t;
        if (layer == 1) { nxt_m = xm2;   nxt_t = xt2;   }
        else            { nxt_m = out_m; nxt_t = out_t; }
        const float* biasT = bl + ((size_t)layer * 2 + 0) * DIM;
        const float* biasM = bl + ((size_t)layer * 2 + 1) * DIM;
        const bf16_t* WcT = Wc + ((size_t)layer * 2 + 0) * 128 * 256;
        const bf16_t* WcM = Wc + ((size_t)layer * 2 + 1) * 128 * 256;

        int gwT = ((Mt + 1) / 2 + 3) / 4;   // waves = ceil(Mt/2), 4 waves/block
        int gwM = ((Mm + 1) / 2 + 3) / 4;

        // edge type 0: musician -> track (dst = track)
        gather_mean_bf16<<<gwT, 256, 0, stream>>>(cm, rs_t, cnt_t, csr_t, agg, Mt);
        if (layer < 2)
            gemm_fused<true ><<<(Mt + 63) / 64, 256, 0, stream>>>(agg, ct, WcT, biasT, nxt_t, Mt);
        else
            gemm_fused<false><<<(Mt + 63) / 64, 256, 0, stream>>>(agg, ct, WcT, biasT, nxt_t, Mt);

        // edge type 1: track -> musician (dst = musician)
        gather_mean_bf16<<<gwM, 256, 0, stream>>>(ct, rs_m, cnt_m, csr_m, agg, Mm);
        if (layer < 2)
            gemm_fused<true ><<<(Mm + 63) / 64, 256, 0, stream>>>(agg, cm, WcM, biasM, nxt_m, Mm);
        else
            gemm_fused<false><<<(Mm + 63) / 64, 256, 0, stream>>>(agg, cm, WcM, biasM, nxt_m, Mm);

        cm = nxt_m;
        ct = nxt_t;
    }
}